// Round 10
// baseline (234.090 us; speedup 1.0000x reference)
//
#include <hip/hip_runtime.h>

#define B_ 128
#define T_ 256
#define C_ 512
#define H_ 512
// softmax scale * log2(e):  (1/sqrt(512)) * 1.44269504
#define CSCALE 0.063763824f

typedef _Float16 f16x8 __attribute__((ext_vector_type(8)));
typedef _Float16 f16x4 __attribute__((ext_vector_type(4)));
typedef _Float16 f16x2 __attribute__((ext_vector_type(2)));
typedef float    f32x4 __attribute__((ext_vector_type(4)));
typedef float    f32x16 __attribute__((ext_vector_type(16)));
typedef unsigned int u32;
typedef u32 u32x4 __attribute__((ext_vector_type(4)));

// async global->LDS, 16B per lane; LDS dest must be wave-uniform base (+lane*16)
__device__ __forceinline__ void gld16(const void* gsrc, void* ldst) {
  __builtin_amdgcn_global_load_lds(
      (__attribute__((address_space(1))) void*)gsrc,
      (__attribute__((address_space(3))) void*)ldst, 16, 0, 0);
}

// ---------------------------------------------------------------- W convert
// Only the weights need a pre-pass now (0.75M elems, ~2us); x is converted
// inline inside proj (fused cvt saves the 26us full-x pass).
__global__ __launch_bounds__(256) void cvtw_kernel(
    const float4* __restrict__ wq, const float4* __restrict__ wk,
    const float4* __restrict__ wv, f16x4* __restrict__ dst) {
  const int NW = (H_ * C_) / 4;  // 65,536
  int i = blockIdx.x * 256 + threadIdx.x;
  if (i >= 3 * NW) return;
  float4 f = (i < NW) ? wq[i] : (i < 2 * NW ? wk[i - NW] : wv[i - 2 * NW]);
  f16x4 u = {(_Float16)f.x, (_Float16)f.y, (_Float16)f.z, (_Float16)f.w};
  dst[i] = u;
}

// ---------------------------------------------------------------- QKV proj
// FUSED-CVT + issue-before-compute ping-pong (minimal T3 recipe):
//   STAGE(buf^1, t+1)  ->  ds_read/cvt/MFMA on buf  ->  vmcnt(0) -> barrier
// Loads for t+1 are in flight DURING compute(t) (R5 staged then drained
// immediately: stall = full latency). Depth 1, vmcnt(0)/step -- avoids R8's
// L2-footprint blowup. x staged as fp32 (16KB/buf), converted on read with
// scalar casts (VALU hides in the stall shadow); W staged f16 (8KB/buf).
// LDS 48KB -> 3 blocks/CU. Conflict-free: A group = 2 sub-blocks of 1KB,
// slot = reader lane, both ds_read_b128 stride-16B/lane; gld16 sources
// pre-permuted to match (G21 both-sides). 4 waves (2M x 2N), 16 MFMA/wave.
// z=0 -> q [B*T,H]; z=1 -> k; z=2 -> v^T [B,H,T].
__global__ __launch_bounds__(256, 3) void proj_kernel(
    const float* __restrict__ xf, const _Float16* __restrict__ whh,
    _Float16* __restrict__ qh, _Float16* __restrict__ kh,
    _Float16* __restrict__ vth) {
  __shared__ float    As[2][4096];   // 2 x 16KB: 8 groups x (2 sub x 64 x f32x4)
  __shared__ _Float16 Bs[2][4096];   // 2 x 8KB:  8 groups x 64 slots x f16x8

  const int tid  = threadIdx.x;
  const int lane = tid & 63;
  const int wave = tid >> 6;          // 0..3
  const int lr = lane & 15, lk = lane >> 4;
  const int lane8 = lane * 8;         // f16 slot offset
  const int lane4 = lane * 4;         // f32 slot offset
  const int m0 = blockIdx.x * 128;
  const int n0 = blockIdx.y * 128;
  const int z  = blockIdx.z;

  const int wm = (wave >> 1) * 64;    // wave's M half
  const int wn = (wave & 1) * 64;     // wave's N half
  const int ga = (wave >> 1) * 4;     // A read-group base
  const int gb = (wave & 1) * 4;      // B read-group base

  // A stage source: group g, sub i; writer lane l -> slot l ->
  //   x[m0 + g*16 + (l&15)][k0 + (l>>4)*8 + i*4]  (fp32, 16B)
  const float* aBase = xf + (size_t)(m0 + lr) * C_ + lk * 8;
  // B stage source: group g = wave / wave+4; lane l -> row +(l&15), col (l>>4)*8
  const _Float16* bBase =
      whh + (size_t)z * (H_ * C_) + (size_t)(n0 + wave * 16 + lr) * C_ + lk * 8;

  f32x4 acc[4][4];
#pragma unroll
  for (int i = 0; i < 4; ++i)
#pragma unroll
    for (int j = 0; j < 4; ++j) acc[i][j] = {0.f, 0.f, 0.f, 0.f};

#define STAGE(BUF, K0) do {                                                   \
    gld16((const void*)(aBase + (size_t)(wave)     * 16 * C_ + (K0)),         \
          (void*)&As[BUF][(wave) * 512]);                                     \
    gld16((const void*)(aBase + (size_t)(wave)     * 16 * C_ + (K0) + 4),     \
          (void*)&As[BUF][(wave) * 512 + 256]);                               \
    gld16((const void*)(aBase + (size_t)(wave + 4) * 16 * C_ + (K0)),         \
          (void*)&As[BUF][(wave + 4) * 512]);                                 \
    gld16((const void*)(aBase + (size_t)(wave + 4) * 16 * C_ + (K0) + 4),     \
          (void*)&As[BUF][(wave + 4) * 512 + 256]);                           \
    gld16((const void*)(bBase + (K0)),                                        \
          (void*)&Bs[BUF][(wave) * 512]);                                     \
    gld16((const void*)(bBase + 64 * C_ + (K0)),                              \
          (void*)&Bs[BUF][(wave + 4) * 512]);                                 \
  } while (0)

  // prologue: tile 0 -> buf0
  STAGE(0, 0);
  asm volatile("s_waitcnt vmcnt(0)" ::: "memory");
  __builtin_amdgcn_s_barrier();

#pragma unroll 2
  for (int t = 0; t < 16; ++t) {
    const int buf = t & 1;
    if (t < 15) STAGE(buf ^ 1, (t + 1) * 32);  // in flight during compute

    f16x8 af[4], bf[4];
#pragma unroll
    for (int mi = 0; mi < 4; ++mi) {
      f32x4 lo = *(const f32x4*)&As[buf][(ga + mi) * 512 + lane4];
      f32x4 hv = *(const f32x4*)&As[buf][(ga + mi) * 512 + 256 + lane4];
      f16x8 a = {(_Float16)lo[0], (_Float16)lo[1], (_Float16)lo[2],
                 (_Float16)lo[3], (_Float16)hv[0], (_Float16)hv[1],
                 (_Float16)hv[2], (_Float16)hv[3]};
      af[mi] = a;
    }
#pragma unroll
    for (int ni = 0; ni < 4; ++ni)
      bf[ni] = *(const f16x8*)&Bs[buf][(gb + ni) * 512 + lane8];

    __builtin_amdgcn_s_setprio(1);
#pragma unroll
    for (int mi = 0; mi < 4; ++mi)
#pragma unroll
      for (int ni = 0; ni < 4; ++ni)
        acc[mi][ni] = __builtin_amdgcn_mfma_f32_16x16x32_f16(
            af[mi], bf[ni], acc[mi][ni], 0, 0, 0);
    __builtin_amdgcn_s_setprio(0);

    asm volatile("s_waitcnt vmcnt(0)" ::: "memory");  // t+1 landed
    __builtin_amdgcn_s_barrier();
  }
#undef STAGE

  // ---- epilogue. D layout: col = lane&15, row = (lane>>4)*4 + r [m89/m91]
  if (z < 2) {
    _Float16* out = (z == 0) ? qh : kh;
#pragma unroll
    for (int mi = 0; mi < 4; ++mi) {
      int mg = m0 + wm + mi * 16 + lk * 4;
#pragma unroll
      for (int ni = 0; ni < 4; ++ni) {
        int n = n0 + wn + ni * 16 + lr;
#pragma unroll
        for (int r = 0; r < 4; ++r)
          out[(size_t)(mg + r) * H_ + n] = (_Float16)acc[mi][ni][r];
      }
    }
  } else {
    // v^T[b][h][t]; r = consecutive t -> 8B packed store
#pragma unroll
    for (int mi = 0; mi < 4; ++mi) {
      int mbase = m0 + wm + mi * 16 + lk * 4;
      int bb = mbase >> 8, tt = mbase & 255;
#pragma unroll
      for (int ni = 0; ni < 4; ++ni) {
        int n = n0 + wn + ni * 16 + lr;
        f16x4 u = {(_Float16)acc[mi][ni][0], (_Float16)acc[mi][ni][1],
                   (_Float16)acc[mi][ni][2], (_Float16)acc[mi][ni][3]};
        *(f16x4*)&vth[(size_t)bb * (H_ * T_) + (size_t)n * T_ + tt] = u;
      }
    }
  }
}

// ---------------------------------------------------------------- attention
// (FROZEN from R8 -- ~59-61 us, no spill at (256,2).)
// Software-pipelined swapped-QK^T; one barrier/tile; Ex double-buffered.
__global__ __launch_bounds__(256, 2) void attn_kernel(
    const _Float16* __restrict__ qh, const _Float16* __restrict__ kh,
    const _Float16* __restrict__ vth, float* __restrict__ dout) {
  __shared__ f32x4 Ex[2][4][4][64];  // [buf][wave][chunk][lane] = 32 KB

  const int tid  = threadIdx.x;
  const int lane = tid & 63;
  const int wq   = tid >> 6;          // 0..3 = H-quarter
  const int lq   = lane & 31;         // this lane's q row (within tile)
  const int hi   = lane >> 5;
  const int flat = blockIdx.x;        // 0..1023
  const int xcd  = flat & 7;
  const int rest = flat >> 3;
  const int qb   = 7 - (rest & 7);    // long-first within each XCD stream
  const int g    = rest >> 3;         // 0..15
  const int b    = xcd + (g << 3);    // batch, pinned to XCD b%8
  const int q0   = qb * 32;
  const int nkv  = qb + 1;            // kv tiles of 32
  const int hbase = wq * 128;
  const int qg   = q0 + lq;           // global q row for this lane

  // Q as B-operand frags: lane holds Q[qg][hbase + ks*16 + hi*8 + j]
  f16x8 qf[8];
  const _Float16* qp = qh + ((size_t)b * T_ + qg) * H_ + hbase + hi * 8;
#pragma unroll
  for (int ks = 0; ks < 8; ++ks) qf[ks] = *(const f16x8*)&qp[ks * 16];

  f32x16 ot[4];  // O^T quarter
#pragma unroll
  for (int i = 0; i < 4; ++i) ot[i] = {};
  float m_ = -1e30f, l_ = 0.f;

  const _Float16* kp = kh  + ((size_t)b * T_ + lq) * H_ + hbase + hi * 8;
  const _Float16* vp = vth + ((size_t)b * H_ + hbase + lq) * T_ + hi * 8;

  // ---- prologue: QK^T(0) partial -> Ex[0]
  f16x8 kf[8];
#pragma unroll
  for (int ks = 0; ks < 8; ++ks) kf[ks] = *(const f16x8*)&kp[ks * 16];
  {
    f32x16 s2 = {};
#pragma unroll
    for (int ks = 0; ks < 8; ++ks)
      s2 = __builtin_amdgcn_mfma_f32_32x32x16_f16(kf[ks], qf[ks], s2, 0, 0, 0);
#pragma unroll
    for (int c = 0; c < 4; ++c) {
      f32x4 w4 = {s2[c*4+0], s2[c*4+1], s2[c*4+2], s2[c*4+3]};
      Ex[0][wq][c][lane] = w4;
    }
  }

  for (int kvt = 0; kvt < nkv; ++kvt) {
    const int kv0 = kvt * 32;
    const int buf = kvt & 1;
    const bool more = (kvt + 1 < nkv);
    __syncthreads();  // Ex[buf] complete; prior reads of Ex[buf^1] done

    // ---- sum all 4 partials (16B/lane contiguous reads, conflict-free)
    f32x16 st;
#pragma unroll
    for (int c = 0; c < 4; ++c) {
      f32x4 r0 = Ex[buf][0][c][lane];
      f32x4 r1 = Ex[buf][1][c][lane];
      f32x4 r2 = Ex[buf][2][c][lane];
      f32x4 r3 = Ex[buf][3][c][lane];
      f32x4 r = (r0 + r1) + (r2 + r3);
      st[c*4+0] = r[0]; st[c*4+1] = r[1]; st[c*4+2] = r[2]; st[c*4+3] = r[3];
    }

    // ---- early-issue next tile's K loads (hide L2 latency under softmax)
    if (more) {
#pragma unroll
      for (int ks = 0; ks < 8; ++ks)
        kf[ks] = *(const f16x8*)&kp[(size_t)(kv0 + 32) * H_ + ks * 16];
    }

    // ---- causal mask + in-register softmax (q = lane-local), in place
    float rm = -1e30f;
    const int kvb = kv0 + 4 * hi;
#pragma unroll
    for (int r = 0; r < 16; ++r) {
      int kvg = kvb + (r & 3) + 8 * (r >> 2);
      float v = (kvg > qg) ? -1e30f : st[r];
      st[r] = v;
      rm = fmaxf(rm, v);
    }
    rm = fmaxf(rm, __shfl_xor(rm, 32, 64));

    // defer-max (T13): rescale only when max grew > 64 raw (~e^4 headroom)
    if (__any((int)(rm > m_ + 64.f))) {
      float mn = fmaxf(m_, rm);
      float al = __builtin_amdgcn_exp2f((m_ - mn) * CSCALE);
      m_ = mn; l_ *= al;
#pragma unroll
      for (int i = 0; i < 4; ++i)
#pragma unroll
        for (int e = 0; e < 16; ++e) ot[i][e] *= al;
    }
    float rs = 0.f;
#pragma unroll
    for (int r = 0; r < 16; ++r) {
      st[r] = __builtin_amdgcn_exp2f((st[r] - m_) * CSCALE);
      rs += st[r];
    }
    rs += __shfl_xor(rs, 32, 64);
    l_ += rs;

    // ---- P -> f16 pack + partner exchange -> PV B-frags (two reg-lean groups)
    f16x8 pb0, pb1;
    {
      f16x2 h0 = {(_Float16)st[0], (_Float16)st[1]};
      f16x2 h1 = {(_Float16)st[2], (_Float16)st[3]};
      f16x2 h2 = {(_Float16)st[4], (_Float16)st[5]};
      f16x2 h3 = {(_Float16)st[6], (_Float16)st[7]};
      u32 w0 = __builtin_bit_cast(u32, h0), w1 = __builtin_bit_cast(u32, h1);
      u32 w2 = __builtin_bit_cast(u32, h2), w3 = __builtin_bit_cast(u32, h3);
      u32 s0 = (u32)__shfl_xor((int)w0, 32, 64);
      u32 s1 = (u32)__shfl_xor((int)w1, 32, 64);
      u32 s2 = (u32)__shfl_xor((int)w2, 32, 64);
      u32 s3 = (u32)__shfl_xor((int)w3, 32, 64);
      u32x4 t0 = { hi ? s2 : w0, hi ? s3 : w1, hi ? w2 : s0, hi ? w3 : s1 };
      pb0 = __builtin_bit_cast(f16x8, t0);
    }
    {
      f16x2 h0 = {(_Float16)st[8],  (_Float16)st[9]};
      f16x2 h1 = {(_Float16)st[10], (_Float16)st[11]};
      f16x2 h2 = {(_Float16)st[12], (_Float16)st[13]};
      f16x2 h3 = {(_Float16)st[14], (_Float16)st[15]};
      u32 w0 = __builtin_bit_cast(u32, h0), w1 = __builtin_bit_cast(u32, h1);
      u32 w2 = __builtin_bit_cast(u32, h2), w3 = __builtin_bit_cast(u32, h3);
      u32 s0 = (u32)__shfl_xor((int)w0, 32, 64);
      u32 s1 = (u32)__shfl_xor((int)w1, 32, 64);
      u32 s2 = (u32)__shfl_xor((int)w2, 32, 64);
      u32 s3 = (u32)__shfl_xor((int)w3, 32, 64);
      u32x4 t1 = { hi ? s2 : w0, hi ? s3 : w1, hi ? w2 : s0, hi ? w3 : s1 };
      pb1 = __builtin_bit_cast(f16x8, t1);
    }

    // ---- PV on H-quarter: O^T[32h x 32q] += V^T[32h x 32kv] * P^T
    __builtin_amdgcn_s_setprio(1);
#pragma unroll
    for (int ht = 0; ht < 4; ++ht) {
      f16x8 va0 = *(const f16x8*)&vp[(size_t)(ht * 32) * T_ + kv0];
      f16x8 va1 = *(const f16x8*)&vp[(size_t)(ht * 32) * T_ + kv0 + 16];
      ot[ht] = __builtin_amdgcn_mfma_f32_32x32x16_f16(va0, pb0, ot[ht], 0, 0, 0);
      ot[ht] = __builtin_amdgcn_mfma_f32_32x32x16_f16(va1, pb1, ot[ht], 0, 0, 0);
    }
    __builtin_amdgcn_s_setprio(0);

    // ---- QK^T(t+1) + Ex-write (crosses the back-edge; off t's critical path)
    if (more) {
      f32x16 s2v = {};
      __builtin_amdgcn_s_setprio(1);
#pragma unroll
      for (int ks = 0; ks < 8; ++ks)
        s2v = __builtin_amdgcn_mfma_f32_32x32x16_f16(kf[ks], qf[ks], s2v, 0, 0, 0);
      __builtin_amdgcn_s_setprio(0);
#pragma unroll
      for (int c = 0; c < 4; ++c) {
        f32x4 w4 = {s2v[c*4+0], s2v[c*4+1], s2v[c*4+2], s2v[c*4+3]};
        Ex[buf ^ 1][wq][c][lane] = w4;
      }
    }
  }

  // ---- normalize + store fp32 (lane's q row, wave's 128 H-cols)
  float li = 1.0f / l_;
  float* op = dout + ((size_t)b * T_ + qg) * H_ + hbase + 4 * hi;
#pragma unroll
  for (int ht = 0; ht < 4; ++ht)
#pragma unroll
    for (int rq = 0; rq < 4; ++rq) {
      f32x4 v4 = {ot[ht][rq*4+0] * li, ot[ht][rq*4+1] * li,
                  ot[ht][rq*4+2] * li, ot[ht][rq*4+3] * li};
      *(f32x4*)&op[ht * 32 + rq * 8] = v4;
    }
}

// ---------------------------------------------------------------- launch
extern "C" void kernel_launch(void* const* d_in, const int* in_sizes, int n_in,
                              void* d_out, int out_size, void* d_ws, size_t ws_size,
                              hipStream_t stream) {
  const size_t NWE = (size_t)3 * H_ * C_;    // 786,432
  const size_t NQE = (size_t)B_ * T_ * H_;   // 16,777,216
  const size_t need = (NWE + 3 * NQE) * sizeof(_Float16);  // 102,236,160 B
  if (ws_size < need) return;  // loud failure (absmax = max|ref|) -> ws too small

  const float* x  = (const float*)d_in[0];
  const float* wq = (const float*)d_in[1];
  const float* wk = (const float*)d_in[2];
  const float* wv = (const float*)d_in[3];

  _Float16* whh = (_Float16*)d_ws;
  _Float16* qh  = whh + NWE;
  _Float16* kh  = qh + NQE;
  _Float16* vth = kh + NQE;

  cvtw_kernel<<<768, 256, 0, stream>>>((const float4*)wq, (const float4*)wk,
                                       (const float4*)wv, (f16x4*)whh);
  proj_kernel<<<dim3(256, 4, 3), dim3(256), 0, stream>>>(x, whh, qh, kh, vth);
  attn_kernel<<<1024, 256, 0, stream>>>(qh, kh, vth, (float*)d_out);
}

// Round 11
// 172.376 us; speedup vs baseline: 1.3580x; 1.3580x over previous
//
#include <hip/hip_runtime.h>

#define B_ 128
#define T_ 256
#define C_ 512
#define H_ 512
// softmax scale * log2(e):  (1/sqrt(512)) * 1.44269504
#define CSCALE 0.063763824f

typedef _Float16 f16x8 __attribute__((ext_vector_type(8)));
typedef _Float16 f16x4 __attribute__((ext_vector_type(4)));
typedef _Float16 f16x2 __attribute__((ext_vector_type(2)));
typedef float    f32x4 __attribute__((ext_vector_type(4)));
typedef float    f32x16 __attribute__((ext_vector_type(16)));
typedef unsigned int u32;
typedef u32 u32x4 __attribute__((ext_vector_type(4)));

// async global->LDS, 16B per lane; LDS dest must be wave-uniform base (+lane*16)
__device__ __forceinline__ void gld16(const void* gsrc, void* ldst) {
  __builtin_amdgcn_global_load_lds(
      (__attribute__((address_space(1))) void*)gsrc,
      (__attribute__((address_space(3))) void*)ldst, 16, 0, 0);
}

// ---------------------------------------------------------------- x convert
// Branch-free streaming pass (the old fused cvt's 4-way branch chain cost
// VALU on a pure-BW kernel). 96 MB -> ~16-18 us at achievable HBM BW.
__global__ __launch_bounds__(256) void cvtx_kernel(
    const float4* __restrict__ x, f16x4* __restrict__ dst) {
  const int NX = (B_ * T_ * C_) / 4;  // 4,194,304
  int gid = blockIdx.x * 256 + threadIdx.x;
  int gsz = gridDim.x * 256;
  for (int i = gid; i < NX; i += gsz) {
    float4 f = x[i];
    f16x4 u = {(_Float16)f.x, (_Float16)f.y, (_Float16)f.z, (_Float16)f.w};
    dst[i] = u;
  }
}

// ---------------------------------------------------------------- W convert
__global__ __launch_bounds__(256) void cvtw_kernel(
    const float4* __restrict__ wq, const float4* __restrict__ wk,
    const float4* __restrict__ wv, f16x4* __restrict__ dst) {
  const int NW = (H_ * C_) / 4;  // 65,536
  int i = blockIdx.x * 256 + threadIdx.x;
  if (i >= 3 * NW) return;
  float4 f = (i < NW) ? wq[i] : (i < 2 * NW ? wk[i - NW] : wv[i - 2 * NW]);
  f16x4 u = {(_Float16)f.x, (_Float16)f.y, (_Float16)f.z, (_Float16)f.w};
  dst[i] = u;
}

// ---------------------------------------------------------------- QKV proj
// (RESTORED R5 -- proven 80 us. Scoreboard: 2-barrier 80 / 8-phase 80 /
// ring 115 / z-merge 101 / fused-fp32 170 -> 80 is structural at K=512.)
// gemm_bt, m97 structure (128x128, BK=32). z=0 -> q; z=1 -> k; z=2 -> v^T.
__global__ __launch_bounds__(256) void proj_kernel(
    const _Float16* __restrict__ xh, const _Float16* __restrict__ wh,
    _Float16* __restrict__ qh, _Float16* __restrict__ kh,
    _Float16* __restrict__ vth) {
  __shared__ _Float16 As[128 * 32];  // 8 KB, row-major [128][32]
  __shared__ _Float16 Bs[128 * 32];  // 8 KB

  const int tid  = threadIdx.x;
  const int lane = tid & 63;
  const int wave = tid >> 6;
  const int lr = lane & 15, lk = lane >> 4;
  const int m0 = blockIdx.x * 128;
  const int n0 = blockIdx.y * 128;
  const int z  = blockIdx.z;
  const _Float16* wz = wh + z * (H_ * C_);

  const int wm = (wave >> 1) * 64;
  const int wn = (wave & 1) * 64;

  f32x4 acc[4][4];
#pragma unroll
  for (int i = 0; i < 4; ++i)
#pragma unroll
    for (int j = 0; j < 4; ++j) acc[i][j] = {0.f, 0.f, 0.f, 0.f};

  // staging: thread t covers row = i*64 + (t>>2), col = (t&3)*8 (8 f16 = 16B)
  const int srow = tid >> 2, scol = (tid & 3) * 8;
  const _Float16* aSrc = xh + (size_t)(m0 + srow) * C_ + scol;
  const _Float16* bSrc = wz + (size_t)(n0 + srow) * C_ + scol;

  for (int k0 = 0; k0 < C_; k0 += 32) {
    __syncthreads();  // previous compute done reading LDS
#pragma unroll
    for (int i = 0; i < 2; ++i) {
      gld16((const void*)(aSrc + i * 64 * C_ + k0), (void*)&As[i * 2048 + wave * 512]);
      gld16((const void*)(bSrc + i * 64 * C_ + k0), (void*)&Bs[i * 2048 + wave * 512]);
    }
    __syncthreads();  // staging drained (vmcnt(0) at barrier)

    f16x8 a[4], b[4];
#pragma unroll
    for (int mi = 0; mi < 4; ++mi)
      a[mi] = *(const f16x8*)&As[(wm + mi * 16 + lr) * 32 + lk * 8];
#pragma unroll
    for (int ni = 0; ni < 4; ++ni)
      b[ni] = *(const f16x8*)&Bs[(wn + ni * 16 + lr) * 32 + lk * 8];
#pragma unroll
    for (int mi = 0; mi < 4; ++mi)
#pragma unroll
      for (int ni = 0; ni < 4; ++ni)
        acc[mi][ni] = __builtin_amdgcn_mfma_f32_16x16x32_f16(a[mi], b[ni], acc[mi][ni], 0, 0, 0);
  }

  // epilogue. D layout: col = lane&15, row = (lane>>4)*4 + r   [m89/m91]
  if (z < 2) {
    _Float16* out = (z == 0) ? qh : kh;
#pragma unroll
    for (int mi = 0; mi < 4; ++mi) {
      int mbase = m0 + wm + mi * 16 + lk * 4;
#pragma unroll
      for (int ni = 0; ni < 4; ++ni) {
        int n = n0 + wn + ni * 16 + lr;
#pragma unroll
        for (int r = 0; r < 4; ++r)
          out[(size_t)(mbase + r) * H_ + n] = (_Float16)acc[mi][ni][r];
      }
    }
  } else {
    // v^T[b][h][t]; r=0..3 are consecutive t -> pack 8B store
#pragma unroll
    for (int mi = 0; mi < 4; ++mi) {
      int mbase = m0 + wm + mi * 16 + lk * 4;
      int bb = mbase >> 8, tt = mbase & 255;
#pragma unroll
      for (int ni = 0; ni < 4; ++ni) {
        int n = n0 + wn + ni * 16 + lr;
        f16x4 u = {(_Float16)acc[mi][ni][0], (_Float16)acc[mi][ni][1],
                   (_Float16)acc[mi][ni][2], (_Float16)acc[mi][ni][3]};
        *(f16x4*)&vth[(size_t)bb * (H_ * T_) + (size_t)n * T_ + tt] = u;
      }
    }
  }
}

// ---------------------------------------------------------------- attention
// R8 pipelined swapped-QK^T + VGPR DIET: persistent kf[8] dropped (-32
// VGPR); K loads moved inline into the QK-next MFMA cluster (back-edge
// overlap work -- its latency is off the consumer path). Live state ~150
// -> fits the (256,3) cap of 170 -> 3 blocks/CU (was 2), +50% independent
// waves hiding the per-tile serial chain. Spill signature (R7): symmetric
// FETCH+WRITE bump -> revert to (256,2) if seen.
__global__ __launch_bounds__(256, 3) void attn_kernel(
    const _Float16* __restrict__ qh, const _Float16* __restrict__ kh,
    const _Float16* __restrict__ vth, float* __restrict__ dout) {
  __shared__ f32x4 Ex[2][4][4][64];  // [buf][wave][chunk][lane] = 32 KB

  const int tid  = threadIdx.x;
  const int lane = tid & 63;
  const int wq   = tid >> 6;          // 0..3 = H-quarter
  const int lq   = lane & 31;         // this lane's q row (within tile)
  const int hi   = lane >> 5;
  const int flat = blockIdx.x;        // 0..1023
  const int xcd  = flat & 7;
  const int rest = flat >> 3;
  const int qb   = 7 - (rest & 7);    // long-first within each XCD stream
  const int g    = rest >> 3;         // 0..15
  const int b    = xcd + (g << 3);    // batch, pinned to XCD b%8
  const int q0   = qb * 32;
  const int nkv  = qb + 1;            // kv tiles of 32
  const int hbase = wq * 128;
  const int qg   = q0 + lq;           // global q row for this lane

  // Q as B-operand frags: lane holds Q[qg][hbase + ks*16 + hi*8 + j]
  f16x8 qf[8];
  const _Float16* qp = qh + ((size_t)b * T_ + qg) * H_ + hbase + hi * 8;
#pragma unroll
  for (int ks = 0; ks < 8; ++ks) qf[ks] = *(const f16x8*)&qp[ks * 16];

  f32x16 ot[4];  // O^T quarter
#pragma unroll
  for (int i = 0; i < 4; ++i) ot[i] = {};
  float m_ = -1e30f, l_ = 0.f;

  const _Float16* kp = kh  + ((size_t)b * T_ + lq) * H_ + hbase + hi * 8;
  const _Float16* vp = vth + ((size_t)b * H_ + hbase + lq) * T_ + hi * 8;

  // ---- prologue: QK^T(0) partial -> Ex[0] (K frags loaded inline)
  {
    f32x16 s2 = {};
#pragma unroll
    for (int ks = 0; ks < 8; ++ks) {
      f16x8 kfv = *(const f16x8*)&kp[ks * 16];
      s2 = __builtin_amdgcn_mfma_f32_32x32x16_f16(kfv, qf[ks], s2, 0, 0, 0);
    }
#pragma unroll
    for (int c = 0; c < 4; ++c) {
      f32x4 w4 = {s2[c*4+0], s2[c*4+1], s2[c*4+2], s2[c*4+3]};
      Ex[0][wq][c][lane] = w4;
    }
  }

  for (int kvt = 0; kvt < nkv; ++kvt) {
    const int kv0 = kvt * 32;
    const int buf = kvt & 1;
    const bool more = (kvt + 1 < nkv);
    __syncthreads();  // Ex[buf] complete; prior reads of Ex[buf^1] done

    // ---- sum all 4 partials (16B/lane contiguous reads, conflict-free)
    f32x16 st;
#pragma unroll
    for (int c = 0; c < 4; ++c) {
      f32x4 r0 = Ex[buf][0][c][lane];
      f32x4 r1 = Ex[buf][1][c][lane];
      f32x4 r2 = Ex[buf][2][c][lane];
      f32x4 r3 = Ex[buf][3][c][lane];
      f32x4 r = (r0 + r1) + (r2 + r3);
      st[c*4+0] = r[0]; st[c*4+1] = r[1]; st[c*4+2] = r[2]; st[c*4+3] = r[3];
    }

    // ---- causal mask + in-register softmax (q = lane-local), in place
    float rm = -1e30f;
    const int kvb = kv0 + 4 * hi;
#pragma unroll
    for (int r = 0; r < 16; ++r) {
      int kvg = kvb + (r & 3) + 8 * (r >> 2);
      float v = (kvg > qg) ? -1e30f : st[r];
      st[r] = v;
      rm = fmaxf(rm, v);
    }
    rm = fmaxf(rm, __shfl_xor(rm, 32, 64));

    // defer-max (T13): rescale only when max grew > 64 raw (~e^4 headroom)
    if (__any((int)(rm > m_ + 64.f))) {
      float mn = fmaxf(m_, rm);
      float al = __builtin_amdgcn_exp2f((m_ - mn) * CSCALE);
      m_ = mn; l_ *= al;
#pragma unroll
      for (int i = 0; i < 4; ++i)
#pragma unroll
        for (int e = 0; e < 16; ++e) ot[i][e] *= al;
    }
    float rs = 0.f;
#pragma unroll
    for (int r = 0; r < 16; ++r) {
      st[r] = __builtin_amdgcn_exp2f((st[r] - m_) * CSCALE);
      rs += st[r];
    }
    rs += __shfl_xor(rs, 32, 64);
    l_ += rs;

    // ---- P -> f16 pack + partner exchange -> PV B-frags (two reg-lean groups)
    f16x8 pb0, pb1;
    {
      f16x2 h0 = {(_Float16)st[0], (_Float16)st[1]};
      f16x2 h1 = {(_Float16)st[2], (_Float16)st[3]};
      f16x2 h2 = {(_Float16)st[4], (_Float16)st[5]};
      f16x2 h3 = {(_Float16)st[6], (_Float16)st[7]};
      u32 w0 = __builtin_bit_cast(u32, h0), w1 = __builtin_bit_cast(u32, h1);
      u32 w2 = __builtin_bit_cast(u32, h2), w3 = __builtin_bit_cast(u32, h3);
      u32 s0 = (u32)__shfl_xor((int)w0, 32, 64);
      u32 s1 = (u32)__shfl_xor((int)w1, 32, 64);
      u32 s2 = (u32)__shfl_xor((int)w2, 32, 64);
      u32 s3 = (u32)__shfl_xor((int)w3, 32, 64);
      u32x4 t0 = { hi ? s2 : w0, hi ? s3 : w1, hi ? w2 : s0, hi ? w3 : s1 };
      pb0 = __builtin_bit_cast(f16x8, t0);
    }
    {
      f16x2 h0 = {(_Float16)st[8],  (_Float16)st[9]};
      f16x2 h1 = {(_Float16)st[10], (_Float16)st[11]};
      f16x2 h2 = {(_Float16)st[12], (_Float16)st[13]};
      f16x2 h3 = {(_Float16)st[14], (_Float16)st[15]};
      u32 w0 = __builtin_bit_cast(u32, h0), w1 = __builtin_bit_cast(u32, h1);
      u32 w2 = __builtin_bit_cast(u32, h2), w3 = __builtin_bit_cast(u32, h3);
      u32 s0 = (u32)__shfl_xor((int)w0, 32, 64);
      u32 s1 = (u32)__shfl_xor((int)w1, 32, 64);
      u32 s2 = (u32)__shfl_xor((int)w2, 32, 64);
      u32 s3 = (u32)__shfl_xor((int)w3, 32, 64);
      u32x4 t1 = { hi ? s2 : w0, hi ? s3 : w1, hi ? w2 : s0, hi ? w3 : s1 };
      pb1 = __builtin_bit_cast(f16x8, t1);
    }

    // ---- PV on H-quarter: O^T[32h x 32q] += V^T[32h x 32kv] * P^T
    __builtin_amdgcn_s_setprio(1);
#pragma unroll
    for (int ht = 0; ht < 4; ++ht) {
      f16x8 va0 = *(const f16x8*)&vp[(size_t)(ht * 32) * T_ + kv0];
      f16x8 va1 = *(const f16x8*)&vp[(size_t)(ht * 32) * T_ + kv0 + 16];
      ot[ht] = __builtin_amdgcn_mfma_f32_32x32x16_f16(va0, pb0, ot[ht], 0, 0, 0);
      ot[ht] = __builtin_amdgcn_mfma_f32_32x32x16_f16(va1, pb1, ot[ht], 0, 0, 0);
    }
    __builtin_amdgcn_s_setprio(0);

    // ---- QK^T(t+1) + Ex-write (back-edge overlap; K frags loaded inline
    // so at most a couple are live at once -- the VGPR diet)
    if (more) {
      f32x16 s2v = {};
      __builtin_amdgcn_s_setprio(1);
#pragma unroll
      for (int ks = 0; ks < 8; ++ks) {
        f16x8 kfv = *(const f16x8*)&kp[(size_t)(kv0 + 32) * H_ + ks * 16];
        s2v = __builtin_amdgcn_mfma_f32_32x32x16_f16(kfv, qf[ks], s2v, 0, 0, 0);
      }
      __builtin_amdgcn_s_setprio(0);
#pragma unroll
      for (int c = 0; c < 4; ++c) {
        f32x4 w4 = {s2v[c*4+0], s2v[c*4+1], s2v[c*4+2], s2v[c*4+3]};
        Ex[buf ^ 1][wq][c][lane] = w4;
      }
    }
  }

  // ---- normalize + store fp32 (lane's q row, wave's 128 H-cols)
  float li = 1.0f / l_;
  float* op = dout + ((size_t)b * T_ + qg) * H_ + hbase + 4 * hi;
#pragma unroll
  for (int ht = 0; ht < 4; ++ht)
#pragma unroll
    for (int rq = 0; rq < 4; ++rq) {
      f32x4 v4 = {ot[ht][rq*4+0] * li, ot[ht][rq*4+1] * li,
                  ot[ht][rq*4+2] * li, ot[ht][rq*4+3] * li};
      *(f32x4*)&op[ht * 32 + rq * 8] = v4;
    }
}

// ---------------------------------------------------------------- launch
extern "C" void kernel_launch(void* const* d_in, const int* in_sizes, int n_in,
                              void* d_out, int out_size, void* d_ws, size_t ws_size,
                              hipStream_t stream) {
  const size_t NXE = (size_t)B_ * T_ * C_;   // 16,777,216
  const size_t NWE = (size_t)3 * H_ * C_;    // 786,432
  const size_t NQE = (size_t)B_ * T_ * H_;   // 16,777,216
  const size_t need = (NXE + NWE + 3 * NQE) * sizeof(_Float16);  // 135,790,592 B
  if (ws_size < need) return;  // loud failure (absmax = max|ref|) -> ws too small

  const float* x  = (const float*)d_in[0];
  const float* wq = (const float*)d_in[1];
  const float* wk = (const float*)d_in[2];
  const float* wv = (const float*)d_in[3];

  _Float16* xh  = (_Float16*)d_ws;
  _Float16* whh = xh + NXE;
  _Float16* qh  = whh + NWE;
  _Float16* kh  = qh + NQE;
  _Float16* vth = kh + NQE;

  cvtx_kernel<<<2048, 256, 0, stream>>>((const float4*)x, (f16x4*)xh);
  cvtw_kernel<<<768, 256, 0, stream>>>((const float4*)wq, (const float4*)wk,
                                       (const float4*)wv, (f16x4*)whh);
  proj_kernel<<<dim3(256, 4, 3), dim3(256), 0, stream>>>(xh, whh, qh, kh, vth);
  attn_kernel<<<1024, 256, 0, stream>>>(qh, kh, vth, (float*)d_out);
}